// Round 6
// baseline (293.917 us; speedup 1.0000x reference)
//
#include <hip/hip_runtime.h>

#define N_NODES  100000
#define N_EDGES  3200000
#define NB       8                    // buckets
#define BN       12544                // nodes per bucket (8*12544 >= 100000)
#define NRT      256                  // routing blocks
#define THR      1024
#define QPB      (N_EDGES / NRT / 4)  // 3125 uint4 quads per routing block
#define CAP      2048                 // per (block,bucket) region cap (mean 1562, sigma 40)
#define SA       64                   // acc blocks per bucket
#define SPS      (NRT / SA)           // 4 route-block regions per acc block
#define GA       (NB * SA)            // 512 acc blocks -> 2 per CU
#define TRD      256                  // reduction block size
#define M17      0x1FFFFu

// ws (u32 words): cnt[NRT*NB] | pedge[NRT*NB*CAP] | partials f32[GA*BN]
//                 | deg u32[N] | dinv[N] | xs[N] | us[N] | uself[N]

// ---- K1: single-read edge routing + fire-and-forget global degree atomics ---
__global__ __launch_bounds__(THR) void k_route(
        const int* __restrict__ ei, unsigned* __restrict__ cnt,
        unsigned* __restrict__ pedge, unsigned* __restrict__ deg) {
    __shared__ __align__(16) unsigned stag[BN];
    __shared__ unsigned bcnt[NB], bbase[NB], bcur[NB];
    const int tid = threadIdx.x, blk = blockIdx.x;
    if (tid < NB) bcnt[tid] = 0u;
    __syncthreads();

    const uint4* s4 = (const uint4*)ei;
    const uint4* d4 = (const uint4*)(ei + N_EDGES);
    const int q0 = blk * QPB;
    uint4 dq[4], sq[4];
    #pragma unroll
    for (int i = 0; i < 4; ++i) {
        const int q = tid + i * THR;
        if (q < QPB) { dq[i] = d4[q0 + q]; sq[i] = s4[q0 + q]; }
    }

    unsigned c01 = 0, c23 = 0;   // byte-packed per-thread bucket histogram
    #pragma unroll
    for (int i = 0; i < 4; ++i) {
        const int q = tid + i * THR;
        if (q < QPB) {
            const unsigned dd[4] = { dq[i].x, dq[i].y, dq[i].z, dq[i].w };
            #pragma unroll
            for (int k = 0; k < 4; ++k) {
                const unsigned d = dd[k];
                atomicAdd(&deg[d], 1u);          // exact integer degree, no return
                const unsigned b = d / BN;
                if (b < 4) c01 += 1u << (8 * b);
                else       c23 += 1u << (8 * (b - 4));
            }
        }
    }
    #pragma unroll
    for (int b = 0; b < 4; ++b) {
        const unsigned v0 = (c01 >> (8 * b)) & 0xFFu;
        const unsigned v1 = (c23 >> (8 * b)) & 0xFFu;
        if (v0) atomicAdd(&bcnt[b], v0);
        if (v1) atomicAdd(&bcnt[b + 4], v1);
    }
    __syncthreads();
    if (tid == 0) {
        unsigned run = 0;
        #pragma unroll
        for (int b = 0; b < NB; ++b) { bbase[b] = run; bcur[b] = run; run += bcnt[b]; }
    }
    __syncthreads();

    #pragma unroll
    for (int i = 0; i < 4; ++i) {
        const int q = tid + i * THR;
        if (q < QPB) {
            const unsigned dd[4] = { dq[i].x, dq[i].y, dq[i].z, dq[i].w };
            const unsigned ss[4] = { sq[i].x, sq[i].y, sq[i].z, sq[i].w };
            #pragma unroll
            for (int k = 0; k < 4; ++k) {
                const unsigned d = dd[k];
                const unsigned b = d / BN;
                const unsigned slot = atomicAdd(&bcur[b], 1u);
                stag[slot] = ss[k] | ((d - b * BN) << 17);   // 12500 total < BN
            }
        }
    }
    __syncthreads();

    #pragma unroll
    for (int b = 0; b < NB; ++b) {
        const unsigned n = bcnt[b] < CAP ? bcnt[b] : CAP;
        const unsigned base = bbase[b];
        unsigned* reg = pedge + ((size_t)(blk * NB + b)) * CAP;
        for (unsigned j = tid; j < n; j += THR) reg[j] = stag[base + j];
    }
    if (tid < NB) cnt[blk * NB + tid] = bcnt[tid] < CAP ? bcnt[tid] : CAP;
}

// ---- K3/K5: scatter one value-class into LDS bucket image (ILP-4, 2 blk/CU) -
__global__ __launch_bounds__(THR, 8) void k_acc(
        const unsigned* __restrict__ pedge, const unsigned* __restrict__ cnt,
        const float* __restrict__ vals, float* __restrict__ partials) {
    __shared__ __align__(16) float facc[BN];
    const int tid = threadIdx.x;
    const int bu = blockIdx.x >> 6, sub = blockIdx.x & 63;   // SA = 64
    for (int i = tid; i < BN / 4; i += THR)
        ((float4*)facc)[i] = make_float4(0.f, 0.f, 0.f, 0.f);
    __syncthreads();
    #pragma unroll
    for (int s = 0; s < SPS; ++s) {
        const int r = (sub * SPS + s) * NB + bu;
        const unsigned n = cnt[r];
        const unsigned* reg = pedge + (size_t)r * CAP;
        const uint4* reg4 = (const uint4*)reg;
        const unsigned n4 = n >> 2;
        for (unsigned j = tid; j < n4; j += THR) {
            const uint4 w = reg4[j];
            const float v0 = vals[w.x & M17];
            const float v1 = vals[w.y & M17];
            const float v2 = vals[w.z & M17];
            const float v3 = vals[w.w & M17];
            atomicAdd(&facc[w.x >> 17], v0);
            atomicAdd(&facc[w.y >> 17], v1);
            atomicAdd(&facc[w.z >> 17], v2);
            atomicAdd(&facc[w.w >> 17], v3);
        }
        for (unsigned j = (n & ~3u) + tid; j < n; j += THR) {
            const unsigned w = reg[j];
            atomicAdd(&facc[w >> 17], vals[w & M17]);
        }
    }
    __syncthreads();
    float4* po = (float4*)(partials + (size_t)blockIdx.x * BN);
    const float4* fi = (const float4*)facc;
    for (int i = tid; i < BN / 4; i += THR) po[i] = fi[i];
}

// ---- f32 partial reduction (SA slices, coalesced) ---------------------------
__device__ __forceinline__ float sum_partials(const float* __restrict__ partials,
                                              int g) {
    const int bu = g / BN, l = g - bu * BN;
    const float* pp = partials + (size_t)(bu * SA) * BN + l;
    float s = 0.f;
    #pragma unroll 16
    for (int k = 0; k < SA; ++k) s += pp[(size_t)k * BN];
    return s;
}

// ---- K2: deg -> dinv, xs (2 nodes/thread, direct deg read) ------------------
__global__ __launch_bounds__(TRD) void k_red1(const float* __restrict__ x,
        const unsigned* __restrict__ deg,
        float* __restrict__ dinv, float* __restrict__ xs) {
    const int t = blockIdx.x * TRD + threadIdx.x;
    const int g0 = 2 * t;
    if (g0 >= N_NODES) return;
    const uint2 dv = *(const uint2*)(deg + g0);
    const float di0 = rsqrtf((float)dv.x + 1.f);   // + self loop
    const float di1 = rsqrtf((float)dv.y + 1.f);
    const float2 xv = *(const float2*)(x + g0);
    *(float2*)(dinv + g0) = make_float2(di0, di1);
    *(float2*)(xs + g0)   = make_float2(xv.x * di0, xv.y * di1);
}

// ---- K4: layer1 + folded layer2 weights -> us, uself ------------------------
__global__ __launch_bounds__(TRD) void k_red2(const float* __restrict__ x,
        const float* __restrict__ partials, const float* __restrict__ dinv,
        const float* __restrict__ W1, const float* __restrict__ b1,
        const float* __restrict__ W2, const float* __restrict__ Wl,
        float* __restrict__ us, float* __restrict__ uself) {
    const int g = blockIdx.x * TRD + threadIdx.x;
    if (g >= N_NODES) return;
    const float sum = sum_partials(partials, g);
    const float di = dinv[g];
    const float s1 = di * sum + x[g] * di * di;
    float u = 0.f;
    #pragma unroll
    for (int c = 0; c < 16; ++c) {
        float vcc = 0.f;
        #pragma unroll
        for (int k = 0; k < 16; ++k) vcc += W2[c * 16 + k] * Wl[k];  // (W2@Wl)[c]
        u += fmaxf(W1[c] * s1 + b1[c], 0.f) * vcc;
    }
    us[g] = u * di;
    uself[g] = u * di * di;
}

// ---- K6: epilogue -----------------------------------------------------------
__global__ __launch_bounds__(TRD) void k_red3(const float* __restrict__ partials,
        const float* __restrict__ dinv, const float* __restrict__ uself,
        const float* __restrict__ W2, const float* __restrict__ b2,
        const float* __restrict__ Wl, const float* __restrict__ bl,
        float* __restrict__ out) {
    const int g = blockIdx.x * TRD + threadIdx.x;
    if (g >= N_NODES) return;
    const float sum = sum_partials(partials, g);
    float vcb = bl[0];
    #pragma unroll
    for (int c = 0; c < 16; ++c) {
        float vcc = 0.f;
        #pragma unroll
        for (int k = 0; k < 16; ++k) vcc += W2[c * 16 + k] * Wl[k];
        vcb += b2[c] * vcc;
    }
    out[g] = dinv[g] * sum + uself[g] + vcb;
}

extern "C" void kernel_launch(void* const* d_in, const int* in_sizes, int n_in,
                              void* d_out, int out_size, void* d_ws, size_t ws_size,
                              hipStream_t stream) {
    const float* x  = (const float*)d_in[0];
    const int*   ei = (const int*)d_in[1];
    const float* W1 = (const float*)d_in[2];
    const float* b1 = (const float*)d_in[3];
    const float* W2 = (const float*)d_in[4];
    const float* b2 = (const float*)d_in[5];
    const float* Wl = (const float*)d_in[6];
    const float* bl = (const float*)d_in[7];
    float* out = (float*)d_out;

    unsigned* cnt      = (unsigned*)d_ws;
    unsigned* pedge    = cnt + NRT * NB;
    float*    partials = (float*)(pedge + (size_t)NRT * NB * CAP);
    unsigned* deg      = (unsigned*)(partials + (size_t)GA * BN);
    float*    dinv     = (float*)(deg + N_NODES);
    float*    xs       = dinv + N_NODES;
    float*    us       = xs + N_NODES;
    float*    uself    = us + N_NODES;

    const int rb1 = (N_NODES / 2 + TRD - 1) / TRD;   // 196
    const int rb  = (N_NODES + TRD - 1) / TRD;       // 391

    hipMemsetAsync(deg, 0, (size_t)N_NODES * sizeof(unsigned), stream);
    k_route<<<NRT, THR, 0, stream>>>(ei, cnt, pedge, deg);
    k_red1 <<<rb1, TRD, 0, stream>>>(x, deg, dinv, xs);
    k_acc  <<<GA,  THR, 0, stream>>>(pedge, cnt, xs, partials);
    k_red2 <<<rb,  TRD, 0, stream>>>(x, partials, dinv, W1, b1, W2, Wl, us, uself);
    k_acc  <<<GA,  THR, 0, stream>>>(pedge, cnt, us, partials);
    k_red3 <<<rb,  TRD, 0, stream>>>(partials, dinv, uself, W2, b2, Wl, bl, out);
}

// Round 7
// 182.116 us; speedup vs baseline: 1.6139x; 1.6139x over previous
//
#include <hip/hip_runtime.h>

#define N_NODES  100000
#define N_EDGES  3200000
#define NQ       (N_EDGES / 4)        // 800000 uint4 quads
#define NB       8                    // buckets
#define BN       12544                // nodes per bucket (8*12544 >= 100000)
#define NRT      192                  // routing blocks
#define NDGH     64                   // degree-histogram blocks
#define QPB      4167                 // ceil(NQ / NRT) quads per routing block
#define QPD      (NQ / NDGH)          // 12500 quads per degree block
#define HW       25088                // u32 words of full-node u8 histogram (>= 100000/4)
#define STAGW    16704                // stag words (>= 4*QPB edges = 16668)
#define THR      1024
#define CAP      2560                 // per (block,bucket) region cap (mean 2083, sigma 43)
#define SA       64                   // acc blocks per bucket
#define SPS      (NRT / SA)           // 3 route-block regions per acc block
#define GA       (NB * SA)            // 512 acc blocks -> 2 per CU
#define TRD      256                  // reduction block size
#define M17      0x1FFFFu

// ws (u32 words): cnt[NRT*NB] | pedge[NRT*NB*CAP] | partials f32[GA*BN]
//                 (pdeg u32[NDGH*HW] aliases partials; read by red1 before acc)
//                 | dinv[N] | xs[N] | us[N] | uself[N]

// ---- K1: grid roles. blocks [0,64): full-node packed-u8 degree histogram ----
//          blocks [64,256): single-read bucket routing (count/prefix/place/flush)
__global__ __launch_bounds__(THR) void k_route_deg(
        const int* __restrict__ ei, unsigned* __restrict__ cnt,
        unsigned* __restrict__ pedge, unsigned* __restrict__ pdeg) {
    __shared__ __align__(16) unsigned smem[HW];   // hist (deg) / stag<=16704 (route)
    __shared__ unsigned bcnt[NB], bbase[NB], bcur[NB];
    const int tid = threadIdx.x;
    const uint4* d4 = (const uint4*)(ei + N_EDGES);

    if (blockIdx.x < NDGH) {
        // ---- degree role: one pass over 1/64 of dst, all-node u8x4 image ---
        for (int i = tid; i < HW; i += THR) smem[i] = 0u;
        __syncthreads();
        const int qb = blockIdx.x * QPD, qe = qb + QPD;
        for (int q = qb + tid; q < qe; q += THR) {
            const uint4 dv = d4[q];
            atomicAdd(&smem[dv.x >> 2], 1u << ((dv.x & 3u) << 3));
            atomicAdd(&smem[dv.y >> 2], 1u << ((dv.y & 3u) << 3));
            atomicAdd(&smem[dv.z >> 2], 1u << ((dv.z & 3u) << 3));
            atomicAdd(&smem[dv.w >> 2], 1u << ((dv.w & 3u) << 3));
        }
        __syncthreads();
        uint4* po = (uint4*)(pdeg + (size_t)blockIdx.x * HW);
        const uint4* fi = (const uint4*)smem;
        for (int i = tid; i < HW / 4; i += THR) po[i] = fi[i];
        return;
    }

    // ---- routing role ------------------------------------------------------
    const int blk = blockIdx.x - NDGH;
    if (tid < NB) bcnt[tid] = 0u;
    __syncthreads();

    const uint4* s4 = (const uint4*)ei;
    const int q0 = blk * QPB;
    const int qlim = (q0 + QPB < NQ) ? q0 + QPB : NQ;
    uint4 dq[5], sq[5];
    #pragma unroll
    for (int i = 0; i < 5; ++i) {
        const int q = q0 + tid + i * THR;
        if (q < qlim) { dq[i] = d4[q]; sq[i] = s4[q]; }
    }

    unsigned c01 = 0, c23 = 0;   // byte-packed per-thread bucket histogram (<=20/bucket)
    #pragma unroll
    for (int i = 0; i < 5; ++i) {
        const int q = q0 + tid + i * THR;
        if (q < qlim) {
            const unsigned dd[4] = { dq[i].x, dq[i].y, dq[i].z, dq[i].w };
            #pragma unroll
            for (int k = 0; k < 4; ++k) {
                const unsigned b = dd[k] / BN;
                if (b < 4) c01 += 1u << (8 * b);
                else       c23 += 1u << (8 * (b - 4));
            }
        }
    }
    #pragma unroll
    for (int b = 0; b < 4; ++b) {
        const unsigned v0 = (c01 >> (8 * b)) & 0xFFu;
        const unsigned v1 = (c23 >> (8 * b)) & 0xFFu;
        if (v0) atomicAdd(&bcnt[b], v0);
        if (v1) atomicAdd(&bcnt[b + 4], v1);
    }
    __syncthreads();
    if (tid == 0) {
        unsigned run = 0;
        #pragma unroll
        for (int b = 0; b < NB; ++b) { bbase[b] = run; bcur[b] = run; run += bcnt[b]; }
    }
    __syncthreads();

    #pragma unroll
    for (int i = 0; i < 5; ++i) {
        const int q = q0 + tid + i * THR;
        if (q < qlim) {
            const unsigned dd[4] = { dq[i].x, dq[i].y, dq[i].z, dq[i].w };
            const unsigned ss[4] = { sq[i].x, sq[i].y, sq[i].z, sq[i].w };
            #pragma unroll
            for (int k = 0; k < 4; ++k) {
                const unsigned d = dd[k];
                const unsigned b = d / BN;
                const unsigned slot = atomicAdd(&bcur[b], 1u);
                smem[slot] = ss[k] | ((d - b * BN) << 17);   // <=16668 total < STAGW
            }
        }
    }
    __syncthreads();

    #pragma unroll
    for (int b = 0; b < NB; ++b) {
        const unsigned n = bcnt[b] < CAP ? bcnt[b] : CAP;
        const unsigned base = bbase[b];
        unsigned* reg = pedge + ((size_t)(blk * NB + b)) * CAP;
        for (unsigned j = tid; j < n; j += THR) reg[j] = smem[base + j];
    }
    if (tid < NB) cnt[blk * NB + tid] = bcnt[tid] < CAP ? bcnt[tid] : CAP;
}

// ---- K3/K5: scatter one value-class into LDS bucket image (ILP-4, 2 blk/CU) -
__global__ __launch_bounds__(THR, 8) void k_acc(
        const unsigned* __restrict__ pedge, const unsigned* __restrict__ cnt,
        const float* __restrict__ vals, float* __restrict__ partials) {
    __shared__ __align__(16) float facc[BN];
    const int tid = threadIdx.x;
    const int bu = blockIdx.x >> 6, sub = blockIdx.x & 63;   // SA = 64
    for (int i = tid; i < BN / 4; i += THR)
        ((float4*)facc)[i] = make_float4(0.f, 0.f, 0.f, 0.f);
    __syncthreads();
    #pragma unroll
    for (int s = 0; s < SPS; ++s) {
        const int r = (sub * SPS + s) * NB + bu;
        const unsigned n = cnt[r];
        const unsigned* reg = pedge + (size_t)r * CAP;
        const uint4* reg4 = (const uint4*)reg;
        const unsigned n4 = n >> 2;
        for (unsigned j = tid; j < n4; j += THR) {
            const uint4 w = reg4[j];
            const float v0 = vals[w.x & M17];
            const float v1 = vals[w.y & M17];
            const float v2 = vals[w.z & M17];
            const float v3 = vals[w.w & M17];
            atomicAdd(&facc[w.x >> 17], v0);
            atomicAdd(&facc[w.y >> 17], v1);
            atomicAdd(&facc[w.z >> 17], v2);
            atomicAdd(&facc[w.w >> 17], v3);
        }
        for (unsigned j = (n & ~3u) + tid; j < n; j += THR) {
            const unsigned w = reg[j];
            atomicAdd(&facc[w >> 17], vals[w & M17]);
        }
    }
    __syncthreads();
    float4* po = (float4*)(partials + (size_t)blockIdx.x * BN);
    const float4* fi = (const float4*)facc;
    for (int i = tid; i < BN / 4; i += THR) po[i] = fi[i];
}

// ---- f32 partial reduction (SA slices, coalesced) ---------------------------
__device__ __forceinline__ float sum_partials(const float* __restrict__ partials,
                                              int g) {
    const int bu = g / BN, l = g - bu * BN;
    const float* pp = partials + (size_t)(bu * SA) * BN + l;
    float s = 0.f;
    #pragma unroll 16
    for (int k = 0; k < SA; ++k) s += pp[(size_t)k * BN];
    return s;
}

// ---- K2: packed-u8 deg slices -> dinv, xs (4 nodes/thread) ------------------
//      byte sums across 64 slices never carry (max total degree << 256)
__global__ __launch_bounds__(TRD) void k_red1(const float* __restrict__ x,
        const unsigned* __restrict__ pdeg,
        float* __restrict__ dinv, float* __restrict__ xs) {
    const int t = blockIdx.x * TRD + threadIdx.x;      // word index = 4 nodes
    const int g0 = 4 * t;
    if (g0 >= N_NODES) return;                         // N divisible by 4
    const unsigned* pp = pdeg + t;
    unsigned s = 0;
    #pragma unroll 16
    for (int k = 0; k < NDGH; ++k) s += pp[(size_t)k * HW];
    const float di0 = rsqrtf((float)( s        & 0xFFu) + 1.f);  // + self loop
    const float di1 = rsqrtf((float)((s >>  8) & 0xFFu) + 1.f);
    const float di2 = rsqrtf((float)((s >> 16) & 0xFFu) + 1.f);
    const float di3 = rsqrtf((float)( s >> 24        ) + 1.f);
    const float4 xv = *(const float4*)(x + g0);
    *(float4*)(dinv + g0) = make_float4(di0, di1, di2, di3);
    *(float4*)(xs + g0)   = make_float4(xv.x * di0, xv.y * di1,
                                        xv.z * di2, xv.w * di3);
}

// ---- K4: layer1 + folded layer2 weights -> us, uself ------------------------
__global__ __launch_bounds__(TRD) void k_red2(const float* __restrict__ x,
        const float* __restrict__ partials, const float* __restrict__ dinv,
        const float* __restrict__ W1, const float* __restrict__ b1,
        const float* __restrict__ W2, const float* __restrict__ Wl,
        float* __restrict__ us, float* __restrict__ uself) {
    const int g = blockIdx.x * TRD + threadIdx.x;
    if (g >= N_NODES) return;
    const float sum = sum_partials(partials, g);
    const float di = dinv[g];
    const float s1 = di * sum + x[g] * di * di;
    float u = 0.f;
    #pragma unroll
    for (int c = 0; c < 16; ++c) {
        float vcc = 0.f;
        #pragma unroll
        for (int k = 0; k < 16; ++k) vcc += W2[c * 16 + k] * Wl[k];  // (W2@Wl)[c]
        u += fmaxf(W1[c] * s1 + b1[c], 0.f) * vcc;
    }
    us[g] = u * di;
    uself[g] = u * di * di;
}

// ---- K6: epilogue -----------------------------------------------------------
__global__ __launch_bounds__(TRD) void k_red3(const float* __restrict__ partials,
        const float* __restrict__ dinv, const float* __restrict__ uself,
        const float* __restrict__ W2, const float* __restrict__ b2,
        const float* __restrict__ Wl, const float* __restrict__ bl,
        float* __restrict__ out) {
    const int g = blockIdx.x * TRD + threadIdx.x;
    if (g >= N_NODES) return;
    const float sum = sum_partials(partials, g);
    float vcb = bl[0];
    #pragma unroll
    for (int c = 0; c < 16; ++c) {
        float vcc = 0.f;
        #pragma unroll
        for (int k = 0; k < 16; ++k) vcc += W2[c * 16 + k] * Wl[k];
        vcb += b2[c] * vcc;
    }
    out[g] = dinv[g] * sum + uself[g] + vcb;
}

extern "C" void kernel_launch(void* const* d_in, const int* in_sizes, int n_in,
                              void* d_out, int out_size, void* d_ws, size_t ws_size,
                              hipStream_t stream) {
    const float* x  = (const float*)d_in[0];
    const int*   ei = (const int*)d_in[1];
    const float* W1 = (const float*)d_in[2];
    const float* b1 = (const float*)d_in[3];
    const float* W2 = (const float*)d_in[4];
    const float* b2 = (const float*)d_in[5];
    const float* Wl = (const float*)d_in[6];
    const float* bl = (const float*)d_in[7];
    float* out = (float*)d_out;

    unsigned* cnt      = (unsigned*)d_ws;
    unsigned* pedge    = cnt + NRT * NB;
    float*    partials = (float*)(pedge + (size_t)NRT * NB * CAP);
    unsigned* pdeg     = (unsigned*)partials;       // alias: consumed by red1 first
    float*    dinv     = partials + (size_t)GA * BN;
    float*    xs       = dinv + N_NODES;
    float*    us       = xs + N_NODES;
    float*    uself    = us + N_NODES;

    const int rb1 = (N_NODES / 4 + TRD - 1) / TRD;   // 98
    const int rb  = (N_NODES + TRD - 1) / TRD;       // 391

    k_route_deg<<<NDGH + NRT, THR, 0, stream>>>(ei, cnt, pedge, pdeg);
    k_red1 <<<rb1, TRD, 0, stream>>>(x, pdeg, dinv, xs);
    k_acc  <<<GA,  THR, 0, stream>>>(pedge, cnt, xs, partials);
    k_red2 <<<rb,  TRD, 0, stream>>>(x, partials, dinv, W1, b1, W2, Wl, us, uself);
    k_acc  <<<GA,  THR, 0, stream>>>(pedge, cnt, us, partials);
    k_red3 <<<rb,  TRD, 0, stream>>>(partials, dinv, uself, W2, b2, Wl, bl, out);
}

// Round 8
// 180.280 us; speedup vs baseline: 1.6303x; 1.0102x over previous
//
#include <hip/hip_runtime.h>

#define N_NODES  100000
#define N_EDGES  3200000
#define NQ       (N_EDGES / 4)        // 800000 uint4 quads
#define NB       8                    // buckets
#define BN       12544                // nodes per bucket (8*12544 >= 100000)
#define HALF     50176                // nodes per deg half-image (= 4*HWH)
#define HWH      12544                // u32 words per deg half-image (50 KB LDS)
#define NRT      256                  // routing blocks
#define NDG      128                  // degree blocks: 2 halves x 64 dst slices
#define QPB      (NQ / NRT)           // 3125 quads per routing block (exact)
#define QDS      (NQ / 64)            // 12500 quads per dst slice (exact)
#define THR      1024
#define CAP      2048                 // per (block,bucket) region cap (mean 1562, +13 sigma)
#define SA       32                   // acc blocks per bucket
#define SPS      (NRT / SA)           // 8 route-block regions per acc block
#define GA       (NB * SA)            // 256 acc blocks
#define TRD      256                  // reduction block size
#define M17      0x1FFFFu

// ws (u32 words): cnt[NRT*NB] | pedge[NRT*NB*CAP] | partials f32[GA*BN]
//                 (pdeg u32[NDG*HWH] aliases partials; consumed by red1 first)
//                 | dinv[N] | xs[N] | us[N] | uself[N]

// ---- K1: grid roles, uniform 50 KB LDS (2 blocks/CU) ------------------------
//   blocks [0,256):   single-read bucket routing (count/prefix/place/flush)
//   blocks [256,384): u8-packed degree histogram of one node-half x dst-slice
__global__ __launch_bounds__(THR) void k_route_deg(
        const int* __restrict__ ei, unsigned* __restrict__ cnt,
        unsigned* __restrict__ pedge, unsigned* __restrict__ pdeg) {
    __shared__ __align__(16) unsigned smem[HWH];  // stag (12500 used) / u8 hist
    __shared__ unsigned bcnt[NB], bbase[NB], bcur[NB];
    const int tid = threadIdx.x;
    const uint4* d4 = (const uint4*)(ei + N_EDGES);

    if (blockIdx.x >= NRT) {
        // ---- degree role ---------------------------------------------------
        const int idx = blockIdx.x - NRT;          // = h*64 + sl
        const unsigned base = (unsigned)(idx >> 6) * HALF;
        const int sl = idx & 63;
        for (int i = tid; i < HWH; i += THR) smem[i] = 0u;
        __syncthreads();
        const int qb = sl * QDS, qe = qb + QDS;
        for (int q = qb + tid; q < qe; q += THR) {
            const uint4 dv = d4[q];
            const unsigned d0 = dv.x - base, d1 = dv.y - base;
            const unsigned d2 = dv.z - base, d3 = dv.w - base;
            if (d0 < HALF) atomicAdd(&smem[d0 >> 2], 1u << ((d0 & 3u) << 3));
            if (d1 < HALF) atomicAdd(&smem[d1 >> 2], 1u << ((d1 & 3u) << 3));
            if (d2 < HALF) atomicAdd(&smem[d2 >> 2], 1u << ((d2 & 3u) << 3));
            if (d3 < HALF) atomicAdd(&smem[d3 >> 2], 1u << ((d3 & 3u) << 3));
        }
        __syncthreads();
        uint4* po = (uint4*)(pdeg + (size_t)idx * HWH);
        const uint4* fi = (const uint4*)smem;
        for (int i = tid; i < HWH / 4; i += THR) po[i] = fi[i];
        return;
    }

    // ---- routing role ------------------------------------------------------
    const int blk = blockIdx.x;
    if (tid < NB) bcnt[tid] = 0u;
    __syncthreads();

    const uint4* s4 = (const uint4*)ei;
    const int q0 = blk * QPB;
    uint4 dq[4], sq[4];
    #pragma unroll
    for (int i = 0; i < 4; ++i) {
        const int q = tid + i * THR;
        if (q < QPB) { dq[i] = d4[q0 + q]; sq[i] = s4[q0 + q]; }
    }

    unsigned c01 = 0, c23 = 0;   // byte-packed per-thread bucket histogram
    #pragma unroll
    for (int i = 0; i < 4; ++i) {
        const int q = tid + i * THR;
        if (q < QPB) {
            const unsigned dd[4] = { dq[i].x, dq[i].y, dq[i].z, dq[i].w };
            #pragma unroll
            for (int k = 0; k < 4; ++k) {
                const unsigned b = dd[k] / BN;
                if (b < 4) c01 += 1u << (8 * b);
                else       c23 += 1u << (8 * (b - 4));
            }
        }
    }
    #pragma unroll
    for (int b = 0; b < 4; ++b) {
        const unsigned v0 = (c01 >> (8 * b)) & 0xFFu;
        const unsigned v1 = (c23 >> (8 * b)) & 0xFFu;
        if (v0) atomicAdd(&bcnt[b], v0);
        if (v1) atomicAdd(&bcnt[b + 4], v1);
    }
    __syncthreads();
    if (tid == 0) {
        unsigned run = 0;
        #pragma unroll
        for (int b = 0; b < NB; ++b) { bbase[b] = run; bcur[b] = run; run += bcnt[b]; }
    }
    __syncthreads();

    #pragma unroll
    for (int i = 0; i < 4; ++i) {
        const int q = tid + i * THR;
        if (q < QPB) {
            const unsigned dd[4] = { dq[i].x, dq[i].y, dq[i].z, dq[i].w };
            const unsigned ss[4] = { sq[i].x, sq[i].y, sq[i].z, sq[i].w };
            #pragma unroll
            for (int k = 0; k < 4; ++k) {
                const unsigned d = dd[k];
                const unsigned b = d / BN;
                const unsigned slot = atomicAdd(&bcur[b], 1u);
                smem[slot] = ss[k] | ((d - b * BN) << 17);   // 12500 total < HWH
            }
        }
    }
    __syncthreads();

    #pragma unroll
    for (int b = 0; b < NB; ++b) {
        const unsigned n = bcnt[b] < CAP ? bcnt[b] : CAP;
        const unsigned base = bbase[b];
        unsigned* reg = pedge + ((size_t)(blk * NB + b)) * CAP;
        for (unsigned j = tid; j < n; j += THR) reg[j] = smem[base + j];
    }
    if (tid < NB) cnt[blk * NB + tid] = bcnt[tid] < CAP ? bcnt[tid] : CAP;
}

// ---- K3/K5: scatter one value-class, paired regions (ILP-8, no VGPR clamp) --
__global__ __launch_bounds__(THR) void k_acc(
        const unsigned* __restrict__ pedge, const unsigned* __restrict__ cnt,
        const float* __restrict__ vals, float* __restrict__ partials) {
    __shared__ __align__(16) float facc[BN];
    const int tid = threadIdx.x;
    const int bu = blockIdx.x >> 5, sub = blockIdx.x & 31;   // SA = 32
    for (int i = tid; i < BN / 4; i += THR)
        ((float4*)facc)[i] = make_float4(0.f, 0.f, 0.f, 0.f);
    __syncthreads();
    #pragma unroll
    for (int p = 0; p < SPS / 2; ++p) {
        const int r0 = (sub * SPS + 2 * p)     * NB + bu;
        const int r1 = (sub * SPS + 2 * p + 1) * NB + bu;
        const unsigned n0 = cnt[r0], n1 = cnt[r1];
        const uint4* g0 = (const uint4*)(pedge + (size_t)r0 * CAP);
        const uint4* g1 = (const uint4*)(pedge + (size_t)r1 * CAP);
        const unsigned q0 = n0 >> 2, q1 = n1 >> 2;
        const unsigned m4 = q0 > q1 ? q0 : q1;
        for (unsigned j = tid; j < m4; j += THR) {
            const bool a0 = j < q0, a1 = j < q1;
            uint4 w0, w1;
            if (a0) w0 = g0[j];
            if (a1) w1 = g1[j];
            float v00, v01, v02, v03, v10, v11, v12, v13;
            if (a0) { v00 = vals[w0.x & M17]; v01 = vals[w0.y & M17];
                      v02 = vals[w0.z & M17]; v03 = vals[w0.w & M17]; }
            if (a1) { v10 = vals[w1.x & M17]; v11 = vals[w1.y & M17];
                      v12 = vals[w1.z & M17]; v13 = vals[w1.w & M17]; }
            if (a0) { atomicAdd(&facc[w0.x >> 17], v00); atomicAdd(&facc[w0.y >> 17], v01);
                      atomicAdd(&facc[w0.z >> 17], v02); atomicAdd(&facc[w0.w >> 17], v03); }
            if (a1) { atomicAdd(&facc[w1.x >> 17], v10); atomicAdd(&facc[w1.y >> 17], v11);
                      atomicAdd(&facc[w1.z >> 17], v12); atomicAdd(&facc[w1.w >> 17], v13); }
        }
        const unsigned* e0 = (const unsigned*)g0;
        for (unsigned j = (n0 & ~3u) + tid; j < n0; j += THR)
            atomicAdd(&facc[e0[j] >> 17], vals[e0[j] & M17]);
        const unsigned* e1 = (const unsigned*)g1;
        for (unsigned j = (n1 & ~3u) + tid; j < n1; j += THR)
            atomicAdd(&facc[e1[j] >> 17], vals[e1[j] & M17]);
    }
    __syncthreads();
    float4* po = (float4*)(partials + (size_t)blockIdx.x * BN);
    const float4* fi = (const float4*)facc;
    for (int i = tid; i < BN / 4; i += THR) po[i] = fi[i];
}

// ---- f32 partial reduction (SA slices, coalesced) ---------------------------
__device__ __forceinline__ float sum_partials(const float* __restrict__ partials,
                                              int g) {
    const int bu = g / BN, l = g - bu * BN;
    const float* pp = partials + (size_t)(bu * SA) * BN + l;
    float s = 0.f;
    #pragma unroll 16
    for (int k = 0; k < SA; ++k) s += pp[(size_t)k * BN];
    return s;
}

// ---- K2: u8-packed deg slices -> dinv, xs (4 nodes/thread, no byte carry) ---
__global__ __launch_bounds__(TRD) void k_red1(const float* __restrict__ x,
        const unsigned* __restrict__ pdeg,
        float* __restrict__ dinv, float* __restrict__ xs) {
    const int t = blockIdx.x * TRD + threadIdx.x;      // word index = 4 nodes
    const int g0 = 4 * t;
    if (g0 >= N_NODES) return;                         // N divisible by 4
    const int h = (g0 >= HALF);
    const int lw = (g0 - h * HALF) >> 2;
    const unsigned* pp = pdeg + (size_t)(h * 64) * HWH + lw;
    unsigned s = 0;
    #pragma unroll 16
    for (int k = 0; k < 64; ++k) s += pp[(size_t)k * HWH];
    const float di0 = rsqrtf((float)( s        & 0xFFu) + 1.f);  // + self loop
    const float di1 = rsqrtf((float)((s >>  8) & 0xFFu) + 1.f);
    const float di2 = rsqrtf((float)((s >> 16) & 0xFFu) + 1.f);
    const float di3 = rsqrtf((float)( s >> 24        ) + 1.f);
    const float4 xv = *(const float4*)(x + g0);
    *(float4*)(dinv + g0) = make_float4(di0, di1, di2, di3);
    *(float4*)(xs + g0)   = make_float4(xv.x * di0, xv.y * di1,
                                        xv.z * di2, xv.w * di3);
}

// ---- K4: layer1 + folded layer2 weights -> us, uself ------------------------
__global__ __launch_bounds__(TRD) void k_red2(const float* __restrict__ x,
        const float* __restrict__ partials, const float* __restrict__ dinv,
        const float* __restrict__ W1, const float* __restrict__ b1,
        const float* __restrict__ W2, const float* __restrict__ Wl,
        float* __restrict__ us, float* __restrict__ uself) {
    const int g = blockIdx.x * TRD + threadIdx.x;
    if (g >= N_NODES) return;
    const float sum = sum_partials(partials, g);
    const float di = dinv[g];
    const float s1 = di * sum + x[g] * di * di;
    float u = 0.f;
    #pragma unroll
    for (int c = 0; c < 16; ++c) {
        float vcc = 0.f;
        #pragma unroll
        for (int k = 0; k < 16; ++k) vcc += W2[c * 16 + k] * Wl[k];  // (W2@Wl)[c]
        u += fmaxf(W1[c] * s1 + b1[c], 0.f) * vcc;
    }
    us[g] = u * di;
    uself[g] = u * di * di;
}

// ---- K6: epilogue -----------------------------------------------------------
__global__ __launch_bounds__(TRD) void k_red3(const float* __restrict__ partials,
        const float* __restrict__ dinv, const float* __restrict__ uself,
        const float* __restrict__ W2, const float* __restrict__ b2,
        const float* __restrict__ Wl, const float* __restrict__ bl,
        float* __restrict__ out) {
    const int g = blockIdx.x * TRD + threadIdx.x;
    if (g >= N_NODES) return;
    const float sum = sum_partials(partials, g);
    float vcb = bl[0];
    #pragma unroll
    for (int c = 0; c < 16; ++c) {
        float vcc = 0.f;
        #pragma unroll
        for (int k = 0; k < 16; ++k) vcc += W2[c * 16 + k] * Wl[k];
        vcb += b2[c] * vcc;
    }
    out[g] = dinv[g] * sum + uself[g] + vcb;
}

extern "C" void kernel_launch(void* const* d_in, const int* in_sizes, int n_in,
                              void* d_out, int out_size, void* d_ws, size_t ws_size,
                              hipStream_t stream) {
    const float* x  = (const float*)d_in[0];
    const int*   ei = (const int*)d_in[1];
    const float* W1 = (const float*)d_in[2];
    const float* b1 = (const float*)d_in[3];
    const float* W2 = (const float*)d_in[4];
    const float* b2 = (const float*)d_in[5];
    const float* Wl = (const float*)d_in[6];
    const float* bl = (const float*)d_in[7];
    float* out = (float*)d_out;

    unsigned* cnt      = (unsigned*)d_ws;
    unsigned* pedge    = cnt + NRT * NB;
    float*    partials = (float*)(pedge + (size_t)NRT * NB * CAP);
    unsigned* pdeg     = (unsigned*)partials;       // alias: consumed by red1 first
    float*    dinv     = partials + (size_t)GA * BN;
    float*    xs       = dinv + N_NODES;
    float*    us       = xs + N_NODES;
    float*    uself    = us + N_NODES;

    const int rb1 = (N_NODES / 4 + TRD - 1) / TRD;   // 98
    const int rb  = (N_NODES + TRD - 1) / TRD;       // 391

    k_route_deg<<<NRT + NDG, THR, 0, stream>>>(ei, cnt, pedge, pdeg);
    k_red1 <<<rb1, TRD, 0, stream>>>(x, pdeg, dinv, xs);
    k_acc  <<<GA,  THR, 0, stream>>>(pedge, cnt, xs, partials);
    k_red2 <<<rb,  TRD, 0, stream>>>(x, partials, dinv, W1, b1, W2, Wl, us, uself);
    k_acc  <<<GA,  THR, 0, stream>>>(pedge, cnt, us, partials);
    k_red3 <<<rb,  TRD, 0, stream>>>(partials, dinv, uself, W2, b2, Wl, bl, out);
}